// Round 4
// baseline (7154.463 us; speedup 1.0000x reference)
//
#include <hip/hip_runtime.h>
#include <math.h>

// ToxicityLSTM: 2-layer LSTM (B=64, T=1024, H=256, gates i,j,f,o, forget
// bias 1.0) + linear head (256->6) + sigmoid + threshold.
//
// Round 4: dataflow flags instead of lockstep barrier.
//   - 256 blocks x 512 threads (1 block/CU). Blocks 0..127 layer1, 128..255
//     layer2. Block = 8 units x 16 batch; thread (ul,kq,bt) holds W slice
//     [4g][32k] in VGPRs, computes acc[4b][4g]; 16-way k-combine in LDS;
//     finisher waves 0-1 (128 threads) own (b,u), keep c in registers.
//   - h1/h2 QUAD-buffered (slot = t&3) in ws. Per-block completion flags
//     (2 per block, one per finisher wave, stored after vmcnt(0) drain of
//     the coherent h stores -> data-before-flag ordering).
//   - Consumption-only waits (per-lane thresholds over the bgrp's 64 blocks):
//       L1@t: L1 peers >= t (tight), L2 >= t-3 (quad-buffer anti-dep, stale)
//       L2@t: L1 >= t+1 (pre-satisfied: L1 drifts 1-3 ahead), L2 peers >= t
//     Quad buffering lets L1 run ahead; slack absorbs per-block jitter that
//     the R3 lockstep barrier amplified every step.
//   - Staging: panel halves are disjoint -> waves 0-3 stage low (x or h1)
//     while waves 4-7 poll+stage high (h1 or h2) concurrently; ONE sync, then
//     all 8 waves gemv their own kq slice, partials, sync, finish+flag.

#define BB 64
#define TT 1024
#define HH 256
#define NTHREADS 512
#define FLAG_BYTES 4096
#define HBUF_FLOATS (BB * HH)            // 16384 floats per slot
#define HSET_FLOATS (4 * HBUF_FLOATS)    // quad-buffered set
#define WT_FLOATS (256 * 4 * 512)        // 524288 floats per layer
#define WS_NEEDED (FLAG_BYTES + (size_t)2 * HSET_FLOATS * 4 + (size_t)2 * WT_FLOATS * 4)
#define HROW 576                         // skewed panel row stride (floats)
#define NEG_INF_THR (-1000000)

typedef float f32x4 __attribute__((ext_vector_type(4)));
typedef int   i32x2 __attribute__((ext_vector_type(2)));

__device__ __forceinline__ void coh_store(float* p, float v) {
  __hip_atomic_store(p, v, __ATOMIC_RELAXED, __HIP_MEMORY_SCOPE_AGENT);
}
__device__ __forceinline__ void coh_store_i(int* p, int v) {
  __hip_atomic_store(p, v, __ATOMIC_RELAXED, __HIP_MEMORY_SCOPE_AGENT);
}

// 4 device-coherent float4 loads in flight, one vmcnt drain.
__device__ __forceinline__ void coh_load4(
    const float* p0, const float* p1, const float* p2, const float* p3,
    f32x4& a0, f32x4& a1, f32x4& a2, f32x4& a3) {
  asm volatile(
      "global_load_dwordx4 %0, %4, off sc0 sc1\n\t"
      "global_load_dwordx4 %1, %5, off sc0 sc1\n\t"
      "global_load_dwordx4 %2, %6, off sc0 sc1\n\t"
      "global_load_dwordx4 %3, %7, off sc0 sc1\n\t"
      "s_waitcnt vmcnt(0)"
      : "=&v"(a0), "=&v"(a1), "=&v"(a2), "=&v"(a3)
      : "v"(p0), "v"(p1), "v"(p2), "v"(p3)
      : "memory");
}

// Wave-level poll: lane l watches block (bgrp, l)'s two flags; exit when
// min(flag0, flag1) >= thr on ALL 64 lanes.
__device__ __forceinline__ void poll_wave(const int* fp, int thr) {
  for (;;) {
    i32x2 f;
    asm volatile(
        "global_load_dwordx2 %0, %1, off sc0 sc1\n\t"
        "s_waitcnt vmcnt(0)"
        : "=v"(f) : "v"(fp) : "memory");
    const int v = f[0] < f[1] ? f[0] : f[1];
    if (__all(v >= thr)) break;
    __builtin_amdgcn_s_sleep(1);
  }
}

// One-time weight transpose: src [512 k][4 g * 256 u] -> dst [256 u][4 g][512 k]
__global__ void transpose_w(const float* __restrict__ src, float* __restrict__ dst) {
  __shared__ float t[64][65];
  const int g  = blockIdx.x;   // 4
  const int kt = blockIdx.y;   // 8 tiles over 512 k
  const int ut = blockIdx.z;   // 4 tiles over 256 u
  const int tx = threadIdx.x & 63;
  const int ty = threadIdx.x >> 6;
  #pragma unroll
  for (int r = ty; r < 64; r += 4)
    t[r][tx] = src[(size_t)(kt * 64 + r) * 1024 + g * 256 + ut * 64 + tx];
  __syncthreads();
  #pragma unroll
  for (int r = ty; r < 64; r += 4)
    dst[((size_t)(ut * 64 + r) * 4 + g) * 512 + kt * 64 + tx] = t[tx][r];
}

__global__ __launch_bounds__(NTHREADS, 2) void lstm2_persistent(
    const float* __restrict__ x,
    const float* __restrict__ b0, const float* __restrict__ b1,
    const float* __restrict__ wt0, const float* __restrict__ wt1,
    float* __restrict__ h1buf, float* __restrict__ h2buf,
    int* __restrict__ flags)
{
  __shared__ float hstage[16 * HROW];   // 36864 B operand panel (skewed)
  __shared__ f32x4 part[128 * 17];      // 34816 B k-partials (padded)

  const int blk   = blockIdx.x;
  const int taskB = blk >= 128;                  // layer2 blocks
  const int tblk  = taskB ? blk - 128 : blk;
  const int bgrp  = tblk >> 5;                   // 4 groups of 16 b
  const int ublk  = tblk & 31;                   // 32 groups of 8 u

  const int tid  = threadIdx.x;
  const int wv   = tid >> 6;
  const int lane = tid & 63;
  const int ul   = tid & 7;
  const int kq   = ((tid >> 8) << 3) | ((tid >> 3) & 7);  // waves0-3: 0-7, waves4-7: 8-15
  const int bt   = (tid >> 6) & 3;
  const bool lowW = (wv < 4);
  const int cS   = (tid & 63) + (lowW ? 0 : 64); // staging f4-column 0..127
  const int rS   = (tid >> 6) & 3;               // staging base row (wave-uniform)
  const int dposS = cS * 4 + (cS >> 3) * 4;      // skewed in-row byte/4 position

  const float* WT   = taskB ? wt1 : wt0;
  const float* bias = taskB ? b1 : b0;

  // ---- loop-invariant weight slice into registers: [4 g][32 k] ----
  f32x4 w[4][8];
  {
    const float* wb = WT + (size_t)(ublk * 8 + ul) * 2048 + kq * 32;
    #pragma unroll
    for (int g = 0; g < 4; ++g)
      #pragma unroll
      for (int cc = 0; cc < 8; ++cc)
        w[g][cc] = *(const f32x4*)(wb + g * 512 + cc * 4);
  }

  // ---- finisher state (threads 0..127 own one (b,u)) ----
  float bi = 0.f, bj = 0.f, bfv = 0.f, bo = 0.f;
  if (tid < 128) {
    const int u = ublk * 8 + (tid & 7);
    bi  = bias[u];
    bj  = bias[256 + u];
    bfv = bias[512 + u];
    bo  = bias[768 + u];
  }
  float cst = 0.f;

  const int* pollp  = flags + ((size_t)bgrp * 64 + lane) * 2;
  int*       myflag = flags + ((size_t)bgrp * 64 + (taskB ? 32 : 0) + ublk) * 2;

  for (int t = 0; t < TT; ++t) {
    // ======== stage: low half (waves 0-3) || poll + high half (waves 4-7) ====
    f32x4 v0, v1, v2, v3;
    if (lowW) {
      if (!taskB) {
        // L1 low = x(t): plain cacheable loads, lanes contiguous in k
        const float* bx = x + ((size_t)(bgrp * 16 + rS) * TT + t) * HH + (tid & 63) * 4;
        const size_t rstep = (size_t)4 * TT * HH;
        v0 = *(const f32x4*)(bx);
        v1 = *(const f32x4*)(bx + rstep);
        v2 = *(const f32x4*)(bx + 2 * rstep);
        v3 = *(const f32x4*)(bx + 3 * rstep);
      } else {
        // L2 low = h1(t): wait for L1 completed t (usually pre-satisfied)
        poll_wave(pollp, (lane < 32) ? (t + 1) : NEG_INF_THR);
        const float* p0 = h1buf + (size_t)(t & 3) * HBUF_FLOATS
                        + (size_t)(bgrp * 16 + rS) * HH + (tid & 63) * 4;
        coh_load4(p0, p0 + 4 * HH, p0 + 8 * HH, p0 + 12 * HH, v0, v1, v2, v3);
      }
    } else {
      // high half: the tight dependency poll, then coherent stage
      const int thr = taskB ? ((lane < 32) ? NEG_INF_THR : t)        // L2 peers >= t
                            : ((lane < 32) ? t : (t - 3));           // L1 peers >= t, L2 anti-dep
      poll_wave(pollp, thr);
      const float* src = (taskB ? h2buf : h1buf) + (size_t)((t - 1) & 3) * HBUF_FLOATS;
      const float* p0 = src + (size_t)(bgrp * 16 + rS) * HH + (tid & 63) * 4;
      coh_load4(p0, p0 + 4 * HH, p0 + 8 * HH, p0 + 12 * HH, v0, v1, v2, v3);
    }
    *(f32x4*)&hstage[(rS + 0)  * HROW + dposS] = v0;
    *(f32x4*)&hstage[(rS + 4)  * HROW + dposS] = v1;
    *(f32x4*)&hstage[(rS + 8)  * HROW + dposS] = v2;
    *(f32x4*)&hstage[(rS + 12) * HROW + dposS] = v3;
    __syncthreads();

    // ======== gemv: all 8 waves, own 32-k slice, acc[4b][4g] ========
    float acc[4][4];
    #pragma unroll
    for (int b4 = 0; b4 < 4; ++b4)
      #pragma unroll
      for (int g = 0; g < 4; ++g) acc[b4][g] = 0.f;

    const int kbase = kq * 36;                // skewed slice start
    #pragma unroll
    for (int b4 = 0; b4 < 4; ++b4) {
      const float* hp = &hstage[(bt * 4 + b4) * HROW + kbase];
      #pragma unroll
      for (int cc = 0; cc < 8; ++cc) {
        const f32x4 h4 = *(const f32x4*)(hp + cc * 4);
        #pragma unroll
        for (int g = 0; g < 4; ++g) {
          acc[b4][g] = fmaf(h4[0], w[g][cc][0], acc[b4][g]);
          acc[b4][g] = fmaf(h4[1], w[g][cc][1], acc[b4][g]);
          acc[b4][g] = fmaf(h4[2], w[g][cc][2], acc[b4][g]);
          acc[b4][g] = fmaf(h4[3], w[g][cc][3], acc[b4][g]);
        }
      }
    }

    // ---- 16-way k-combine via padded LDS partials ----
    #pragma unroll
    for (int b4 = 0; b4 < 4; ++b4) {
      f32x4 p = { acc[b4][0], acc[b4][1], acc[b4][2], acc[b4][3] };
      part[((bt * 4 + b4) * 8 + ul) * 17 + kq] = p;
    }
    __syncthreads();

    // ======== finish (waves 0-1) + flag ========
    if (tid < 128) {
      float gi = bi, gj = bj, gf = bfv, go = bo;
      #pragma unroll
      for (int q = 0; q < 16; ++q) {
        const f32x4 p = part[tid * 17 + q];
        gi += p[0]; gj += p[1]; gf += p[2]; go += p[3];
      }
      const float ig = 1.f / (1.f + expf(-gi));
      const float jt = tanhf(gj);
      const float fg = 1.f / (1.f + expf(-(gf + 1.0f)));
      const float og = 1.f / (1.f + expf(-go));
      cst = fg * cst + ig * jt;
      const float hn = og * tanhf(cst);

      float* hb = (taskB ? h2buf : h1buf) + (size_t)(t & 3) * HBUF_FLOATS;
      coh_store(hb + (size_t)(bgrp * 16 + (tid >> 3)) * HH + ublk * 8 + (tid & 7), hn);
      asm volatile("s_waitcnt vmcnt(0)" ::: "memory");   // data before flag
      if ((tid & 63) == 0) coh_store_i(myflag + (tid >> 6), t + 1);
    }
  }
}

// Head: logits = h2_last @ w_out + b_out; sigmoid; threshold.
__global__ void head_kernel(const float* __restrict__ h2last,
                            const float* __restrict__ w_out,
                            const float* __restrict__ b_out,
                            float* __restrict__ out)
{
  int tid = threadIdx.x;
  if (tid >= 384) return;
  int bb = tid / 6, cc = tid % 6;
  float acc = b_out[cc];
  const float* hr = h2last + bb * HH;
  #pragma unroll 4
  for (int uu = 0; uu < HH; ++uu) acc = fmaf(hr[uu], w_out[uu * 6 + cc], acc);
  out[tid] = acc;                            // logits
  float sg = 1.f / (1.f + expf(-acc));
  out[384 + tid] = sg;                       // sigmoid output
  out[768 + tid] = (sg > 0.5f) ? 1.f : 0.f;  // prediction
}

extern "C" void kernel_launch(void* const* d_in, const int* in_sizes, int n_in,
                              void* d_out, int out_size, void* d_ws, size_t ws_size,
                              hipStream_t stream) {
  const float* x     = (const float*)d_in[0];
  const float* k0    = (const float*)d_in[1];
  const float* b0    = (const float*)d_in[2];
  const float* k1    = (const float*)d_in[3];
  const float* b1    = (const float*)d_in[4];
  const float* w_out = (const float*)d_in[5];
  const float* b_out = (const float*)d_in[6];
  float* out = (float*)d_out;

  if (ws_size < WS_NEEDED) return;  // visible failure if ws too small

  int*   flags = (int*)d_ws;
  float* h1b   = (float*)((char*)d_ws + FLAG_BYTES);
  float* h2b   = h1b + HSET_FLOATS;
  float* wt0   = h2b + HSET_FLOATS;
  float* wt1   = wt0 + WT_FLOATS;

  // Zero flags + all h slots (h(-1)=c(-1)=0, slot 3 is the t=-1 slot):
  // graph-replay deterministic.
  hipMemsetAsync(d_ws, 0, FLAG_BYTES + (size_t)2 * HSET_FLOATS * 4, stream);

  transpose_w<<<dim3(4, 8, 4), 256, 0, stream>>>(k0, wt0);
  transpose_w<<<dim3(4, 8, 4), 256, 0, stream>>>(k1, wt1);

  lstm2_persistent<<<256, NTHREADS, 0, stream>>>(x, b0, b1, wt0, wt1,
                                                 h1b, h2b, flags);

  // h2(1023) lives in slot 1023 & 3 = 3
  head_kernel<<<1, 384, 0, stream>>>(h2b + 3 * HBUF_FLOATS, w_out, b_out, out);
}